// Round 7
// baseline (183.622 us; speedup 1.0000x reference)
//
#include <hip/hip_runtime.h>
#include <stdint.h>

#define E 8
#define D 512
#define F 2048
#define NTOK 4096
#define MAXSLOTS 40

typedef __attribute__((ext_vector_type(8))) short bf16x8;
typedef __attribute__((ext_vector_type(4))) float f32x4;
typedef unsigned short u16;

// ---------- workspace layout (bytes) ----------
#define WS_OFFSETS  64                        // 9 ints
#define WS_NSLOT    128                       // 1 int
#define WS_SLOTE    192                       // 40 ints
#define WS_SLOTMT   384                       // 40 ints
#define WS_IDX      1024                      // 4096 ints
#define WS_PERM     (1024 + 4*NTOK)           // 4096 ints
#define WS_XG       65536                     // bf16 [4096][512]  (gathered x)
#define WS_W1T      (WS_XG + 2*NTOK*D)        // bf16 [8][2048][512]  (W1^T)
#define WS_W2T      (WS_W1T + 2*E*D*F)        // bf16 [8][512][2048]  (W2^T)
#define WS_H        (WS_W2T + 2*E*D*F)        // bf16 [4096][2048]  (hidden)
// P0 overlays xg+w1t (dead after gemm1): splits 0,1. P1 after h: splits 2,3.
#define WS_P0       WS_XG                     // fp32 [2][4096][512]
#define WS_P1       (WS_H + 2*NTOK*F)         // fp32 [2][4096][512]

static __device__ __forceinline__ u16 f2b(float f) {
  union { float f; unsigned u; } v; v.f = f;
  unsigned r = v.u + 0x7fffu + ((v.u >> 16) & 1u);   // RNE fp32->bf16
  return (u16)(r >> 16);
}

static __device__ __forceinline__ void gload16(const void* g, void* l) {
  __builtin_amdgcn_global_load_lds(
      (const __attribute__((address_space(1))) unsigned int*)g,
      (__attribute__((address_space(3))) unsigned int*)l, 16, 0, 0);
}

// ---------- gate: fp32-exact logits + argmax (NO atomics) ----------
__global__ __launch_bounds__(256) void gate_k(const float* __restrict__ x,
                                              const float* __restrict__ Wg,
                                              const float* __restrict__ bg,
                                              int* __restrict__ idx) {
  int tok = blockIdx.x * 4 + (threadIdx.x >> 6);   // one wave per token
  int l = threadIdx.x & 63;
  const float* xr = x + (size_t)tok * D;
  float acc[E];
#pragma unroll
  for (int e = 0; e < E; ++e) acc[e] = 0.f;
#pragma unroll
  for (int j = 0; j < 2; ++j) {
    float4 xv = *(const float4*)(xr + l * 8 + j * 4);
    float xs[4] = {xv.x, xv.y, xv.z, xv.w};
#pragma unroll
    for (int c = 0; c < 4; ++c) {
      int d = l * 8 + j * 4 + c;
      float4 w0 = *(const float4*)(Wg + d * 8);
      float4 w1 = *(const float4*)(Wg + d * 8 + 4);
      acc[0] += xs[c] * w0.x; acc[1] += xs[c] * w0.y;
      acc[2] += xs[c] * w0.z; acc[3] += xs[c] * w0.w;
      acc[4] += xs[c] * w1.x; acc[5] += xs[c] * w1.y;
      acc[6] += xs[c] * w1.z; acc[7] += xs[c] * w1.w;
    }
  }
#pragma unroll
  for (int off = 32; off; off >>= 1)
#pragma unroll
    for (int e = 0; e < E; ++e) acc[e] += __shfl_xor(acc[e], off, 64);
  if (l == 0) {
    float bv = acc[0] + bg[0]; int bi = 0;
#pragma unroll
    for (int e = 1; e < E; ++e) {           // strict > : first-max tie-break (matches argmax)
      float v = acc[e] + bg[e];
      if (v > bv) { bv = v; bi = e; }
    }
    idx[tok] = bi;
  }
}

// ---------- single block: LDS histogram -> offsets -> permutation + tile map --
__global__ __launch_bounds__(1024) void hist_perm_k(const int* __restrict__ idx,
                                                    int* __restrict__ offsets,
                                                    int* __restrict__ perm,
                                                    int* __restrict__ nslot,
                                                    int* __restrict__ slot_e,
                                                    int* __restrict__ slot_mt) {
  __shared__ int wcnt[16][E];    // per-wave histograms / later cursors
  __shared__ int wbase[16][E];
  __shared__ int offs[E + 1];
  int t = threadIdx.x;
  int w = t >> 6;
  if (t < 16 * E) ((int*)wcnt)[t] = 0;
  __syncthreads();
  int e0[4];
#pragma unroll
  for (int j = 0; j < 4; ++j) {
    e0[j] = idx[t * 4 + j];
    atomicAdd(&wcnt[w][e0[j]], 1);
  }
  __syncthreads();
  if (t < 64) {
    // linear index li = e*16 + ww (expert-major) matches cursor-assignment order
    int li0 = 2 * t, li1 = 2 * t + 1;
    int c0 = wcnt[li0 & 15][li0 >> 4];
    int c1 = wcnt[li1 & 15][li1 >> 4];
    int s = c0 + c1;
    int incl = s;
#pragma unroll
    for (int o = 1; o < 64; o <<= 1) {
      int v = __shfl_up(incl, o, 64);
      if (t >= o) incl += v;
    }
    int excl = incl - s;
    wbase[li0 & 15][li0 >> 4] = excl;
    wbase[li1 & 15][li1 >> 4] = excl + c0;
    if ((li0 & 15) == 0) offs[li0 >> 4] = excl;   // start of expert li0>>4
    if (t == 63) offs[E] = incl;                  // total
  }
  __syncthreads();
  if (t < E + 1) offsets[t] = offs[t];
  if (t == 0) {                 // build (expert, m-tile) slot map (<=40 entries)
    int ns = 0;
    for (int e = 0; e < E; ++e) {
      int c = offs[e + 1] - offs[e];
      int nmt = (c + 127) >> 7;
      for (int m = 0; m < nmt; ++m) { slot_e[ns] = e; slot_mt[ns] = m; ++ns; }
    }
    *nslot = ns;
  }
  if (t < 16 * E) ((int*)wcnt)[t] = ((int*)wbase)[t];   // reuse as cursors
  __syncthreads();
#pragma unroll
  for (int j = 0; j < 4; ++j) {
    int pos = atomicAdd(&wcnt[w][e0[j]], 1);
    perm[pos] = t * 4 + j;
  }
}

// ---------- gather x rows in permuted order, convert to bf16 ----------
__global__ __launch_bounds__(256) void gather_x(const float* __restrict__ x,
                                                const int* __restrict__ perm,
                                                u16* __restrict__ xg) {
  int t = blockIdx.x * 256 + threadIdx.x;
  int r = t >> 7;              // 128 threads per row
  int c = (t & 127) << 2;
  float4 v = *(const float4*)(x + (size_t)perm[r] * D + c);
  ushort4 o; o.x = f2b(v.x); o.y = f2b(v.y); o.z = f2b(v.z); o.w = f2b(v.w);
  *(ushort4*)(xg + (size_t)r * D + c) = o;
}

// ---------- transpose+convert: src fp32 [E][R][C] -> dst bf16 [E][C][R] ----------
__global__ __launch_bounds__(256) void transpose_cvt(const float* __restrict__ src,
                                                     u16* __restrict__ dst,
                                                     int R, int C) {
  __shared__ float tile[64][65];
  int e = blockIdx.y;
  int tilesC = C >> 6;
  int bt = blockIdx.x;
  int trow = (bt / tilesC) << 6;
  int tcol = (bt % tilesC) << 6;
  const float* s = src + (size_t)e * R * C;
  u16* d = dst + (size_t)e * R * C;
  int lr = threadIdx.x >> 4;          // 0..15
  int lc = (threadIdx.x & 15) << 2;   // 0..60
#pragma unroll
  for (int i = 0; i < 64; i += 16) {
    float4 v = *(const float4*)(s + (size_t)(trow + lr + i) * C + tcol + lc);
    tile[lr + i][lc + 0] = v.x; tile[lr + i][lc + 1] = v.y;
    tile[lr + i][lc + 2] = v.z; tile[lr + i][lc + 3] = v.w;
  }
  __syncthreads();
#pragma unroll
  for (int i = 0; i < 64; i += 16) {
    int c = lr + i;                   // col of src tile = row of dst
    ushort4 o;
    o.x = f2b(tile[lc + 0][c]); o.y = f2b(tile[lc + 1][c]);
    o.z = f2b(tile[lc + 2][c]); o.w = f2b(tile[lc + 3][c]);
    *(ushort4*)(d + (size_t)(tcol + c) * R + trow + lc) = o;
  }
}

// ---------- grouped GEMM, 128x128 tile, BK=32, 3-stage counted-vmcnt ------
// ---------- pipeline (T3+T4), T2 swizzle, T1 XCD swizzle, slot map --------
// A: bf16 [4096][K] row-major (rows grouped by expert); B: bf16 [E][N][K] (B^T)
// FUSE1: out = relu(acc + bias) -> bf16 Hout[4096][N]
// else : plain store acc        -> fp32 P[ks][4096][512] partials
template <int K, int NBLK, int SPLITK, bool FUSE1>
__global__ __launch_bounds__(256) void gemm_grouped(
    const u16* __restrict__ A, const u16* __restrict__ B,
    const float* __restrict__ bias, const int* __restrict__ offsets,
    const int* __restrict__ nslot, const int* __restrict__ slot_e,
    const int* __restrict__ slot_mt,
    u16* __restrict__ Hout, float* __restrict__ P0, float* __restrict__ P1) {
  constexpr int N = NBLK * 128;
  constexpr int KB = K / SPLITK;          // K handled per block
  constexpr int BK = 32;
  constexpr int NT = KB / BK;             // 16 steps for both GEMMs
  constexpr int TSZ = 128 * BK;           // u16 per A- or B-stage (8 KB)
  __shared__ u16 smem[3 * 2 * TSZ];       // 3 stages x {A,B} = 48 KB

  // T1: bijective XCD swizzle (gridDim.x % 8 == 0); nt fastest for B reuse.
  int nwg = gridDim.x;
  int b0 = blockIdx.x;
  int bid = (b0 & 7) * (nwg >> 3) + (b0 >> 3);
  int nt = bid % NBLK; int rem = bid / NBLK;
  int ks = rem % SPLITK;
  int slot = rem / SPLITK;
  if (slot >= *nslot) return;
  int e = slot_e[slot];
  int mt = slot_mt[slot];
  int off = offsets[e];
  int cnt = offsets[e + 1] - off;

  int t = threadIdx.x;
  int w = t >> 6;
  int l = t & 63;

  // staging: round r (0,1) covers rows r*64 + (t>>2), 16B chunk t&3 of BK=32.
  // T2: source chunk pre-swizzled so LINEAR gload_lds dest leaves LDS phys
  // chunk p of row r holding logical chunk p^(r&3).
  int srow = t >> 2;
  int cchunk = (t & 3) ^ ((t >> 2) & 3);
  const u16* Ap[2];
  const u16* Bp[2];
  const u16* Beb = B + (size_t)e * N * K + (size_t)(nt * 128) * K + (size_t)ks * KB;
#pragma unroll
  for (int r = 0; r < 2; ++r) {
    int rl = r * 64 + srow;
    int ga = off + mt * 128 + rl; if (ga > NTOK - 1) ga = NTOK - 1;
    Ap[r] = A + (size_t)ga * K + (size_t)ks * KB + cchunk * 8;
    Bp[r] = Beb + (size_t)rl * K + cchunk * 8;
  }

  int wr = (w >> 1) * 64;                 // wave output sub-tile 64x64
  int wc = (w & 1) * 64;
  int lm = l & 15;
  int g = l >> 4;                         // K-chunk index 0..3 (8 elems each)

  f32x4 acc[4][4] = {};

  auto stage = [&](int buf, int k0) {     // 4 VMEM ops per thread, symmetric
    u16* bA = smem + buf * (2 * TSZ);
    u16* bB = bA + TSZ;
    gload16(Ap[0] + k0, bA + t * 8);
    gload16(Ap[1] + k0, bA + 2048 + t * 8);
    gload16(Bp[0] + k0, bB + t * 8);
    gload16(Bp[1] + k0, bB + 2048 + t * 8);
  };
  auto compute = [&](int buf) {
    const u16* bA = smem + buf * (2 * TSZ);
    const u16* bB = bA + TSZ;
    bf16x8 av[4], bv[4];
#pragma unroll
    for (int fm = 0; fm < 4; ++fm)
      av[fm] = *(const bf16x8*)&bA[(wr + fm * 16 + lm) * 32 + ((g ^ (lm & 3)) * 8)];
#pragma unroll
    for (int fn = 0; fn < 4; ++fn)
      bv[fn] = *(const bf16x8*)&bB[(wc + fn * 16 + lm) * 32 + ((g ^ (lm & 3)) * 8)];
    __builtin_amdgcn_s_setprio(1);
#pragma unroll
    for (int fm = 0; fm < 4; ++fm)
#pragma unroll
      for (int fn = 0; fn < 4; ++fn)
        acc[fm][fn] = __builtin_amdgcn_mfma_f32_16x16x32_bf16(av[fm], bv[fn],
                                                              acc[fm][fn], 0, 0, 0);
    __builtin_amdgcn_s_setprio(0);
  };

  // 3-deep pipeline, counted vmcnt (never 0 in steady state), raw barriers.
  // Per-wave vmcnt is a valid block proxy: all waves issue identical counts.
  stage(0, 0);
  stage(1, BK);                            // 8 VMEM in flight
  for (int ts = 0; ts < NT - 2; ++ts) {
    stage((ts + 2) % 3, (ts + 2) * BK);    // 12 in flight
    asm volatile("s_waitcnt vmcnt(8)" ::: "memory");   // stage ts complete
    __builtin_amdgcn_s_barrier();
    __builtin_amdgcn_sched_barrier(0);
    compute(ts % 3);
    __builtin_amdgcn_sched_barrier(0);
    __builtin_amdgcn_s_barrier();          // all reads of buf ts done -> reusable
  }
  asm volatile("s_waitcnt vmcnt(4)" ::: "memory");
  __builtin_amdgcn_s_barrier();
  __builtin_amdgcn_sched_barrier(0);
  compute((NT - 2) % 3);
  __builtin_amdgcn_sched_barrier(0);
  __builtin_amdgcn_s_barrier();
  asm volatile("s_waitcnt vmcnt(0)" ::: "memory");
  __builtin_amdgcn_s_barrier();
  __builtin_amdgcn_sched_barrier(0);
  compute((NT - 1) % 3);

  // epilogue: C/D layout col = lane&15, row = (lane>>4)*4 + reg
  int nbase = nt * 128 + wc;
  float bb[4];
  if constexpr (FUSE1) {
#pragma unroll
    for (int fn = 0; fn < 4; ++fn) bb[fn] = bias[e * N + nbase + fn * 16 + lm];
  }
  float* Pp = nullptr;
  if constexpr (!FUSE1)
    Pp = (ks < 2) ? P0 + (size_t)ks * (NTOK * D) : P1 + (size_t)(ks - 2) * (NTOK * D);
#pragma unroll
  for (int fm = 0; fm < 4; ++fm) {
    int mbase = wr + fm * 16 + (l >> 4) * 4;
#pragma unroll
    for (int r = 0; r < 4; ++r) {
      int m = mt * 128 + mbase + r;
      if (m < cnt) {
        size_t grow = (size_t)(off + m);
#pragma unroll
        for (int fn = 0; fn < 4; ++fn) {
          int n = nbase + fn * 16 + lm;
          if constexpr (FUSE1) {
            float v = acc[fm][fn][r] + bb[fn];
            Hout[grow * N + n] = f2b(fmaxf(v, 0.f));
          } else {
            Pp[grow * D + n] = acc[fm][fn][r];
          }
        }
      }
    }
  }
}

// ---------- reduce split-K partials + bias, scatter through perm ----------
__global__ __launch_bounds__(256) void reduce_k(const float* __restrict__ P0,
                                                const float* __restrict__ P1,
                                                const float* __restrict__ b2,
                                                const int* __restrict__ offsets,
                                                const int* __restrict__ perm,
                                                float* __restrict__ out) {
  int t = blockIdx.x * 256 + threadIdx.x;
  int g = t >> 7;              // sorted row
  int c = (t & 127) << 2;
  int e = 0;
#pragma unroll
  for (int k = 1; k < E; ++k) e += (g >= offsets[k]);
  size_t pi = (size_t)g * D + c;
  float4 a0 = *(const float4*)(P0 + pi);
  float4 a1 = *(const float4*)(P0 + (size_t)NTOK * D + pi);
  float4 a2 = *(const float4*)(P1 + pi);
  float4 a3 = *(const float4*)(P1 + (size_t)NTOK * D + pi);
  float4 bb = *(const float4*)(b2 + (size_t)e * D + c);
  float4 r;
  r.x = bb.x + ((a0.x + a1.x) + (a2.x + a3.x));
  r.y = bb.y + ((a0.y + a1.y) + (a2.y + a3.y));
  r.z = bb.z + ((a0.z + a1.z) + (a2.z + a3.z));
  r.w = bb.w + ((a0.w + a1.w) + (a2.w + a3.w));
  *(float4*)(out + (size_t)perm[g] * D + c) = r;
}

extern "C" void kernel_launch(void* const* d_in, const int* in_sizes, int n_in,
                              void* d_out, int out_size, void* d_ws, size_t ws_size,
                              hipStream_t stream) {
  const float* x  = (const float*)d_in[0];
  const float* Wg = (const float*)d_in[1];
  const float* bg = (const float*)d_in[2];
  const float* W1 = (const float*)d_in[3];
  const float* b1 = (const float*)d_in[4];
  const float* W2 = (const float*)d_in[5];
  const float* b2 = (const float*)d_in[6];
  float* out = (float*)d_out;
  char* ws = (char*)d_ws;

  int* offsets = (int*)(ws + WS_OFFSETS);
  int* nslot   = (int*)(ws + WS_NSLOT);
  int* slot_e  = (int*)(ws + WS_SLOTE);
  int* slot_mt = (int*)(ws + WS_SLOTMT);
  int* idx     = (int*)(ws + WS_IDX);
  int* perm    = (int*)(ws + WS_PERM);
  u16* xg  = (u16*)(ws + WS_XG);
  u16* w1t = (u16*)(ws + WS_W1T);
  u16* w2t = (u16*)(ws + WS_W2T);
  u16* h   = (u16*)(ws + WS_H);
  float* P0 = (float*)(ws + WS_P0);
  float* P1 = (float*)(ws + WS_P1);

  gate_k<<<NTOK / 4, 256, 0, stream>>>(x, Wg, bg, idx);
  hist_perm_k<<<1, 1024, 0, stream>>>(idx, offsets, perm, nslot, slot_e, slot_mt);
  gather_x<<<NTOK * D / 4 / 256, 256, 0, stream>>>(x, perm, xg);
  transpose_cvt<<<dim3((D / 64) * (F / 64), E), 256, 0, stream>>>(W1, w1t, D, F);
  transpose_cvt<<<dim3((F / 64) * (D / 64), E), 256, 0, stream>>>(W2, w2t, F, D);
  gemm_grouped<D, F / 128, 1, true>
      <<<MAXSLOTS * (F / 128), 256, 0, stream>>>(xg, w1t, b1, offsets, nslot,
                                                 slot_e, slot_mt, h, nullptr, nullptr);
  gemm_grouped<F, D / 128, 4, false>
      <<<MAXSLOTS * (D / 128) * 4, 256, 0, stream>>>(h, w2t, nullptr, offsets, nslot,
                                                     slot_e, slot_mt, nullptr, P0, P1);
  reduce_k<<<NTOK * D / 4 / 256, 256, 0, stream>>>(P0, P1, b2, offsets, perm, out);
}

// Round 8
// 173.478 us; speedup vs baseline: 1.0585x; 1.0585x over previous
//
#include <hip/hip_runtime.h>
#include <stdint.h>

#define E 8
#define D 512
#define F 2048
#define NTOK 4096
#define MAXSLOTS 40      // 128-row tiles: <= 7 + 32
#define MAXSLOTS64 72    // 64-row tiles:  <= 7 + 64

typedef __attribute__((ext_vector_type(8))) short bf16x8;
typedef __attribute__((ext_vector_type(4))) float f32x4;
typedef unsigned short u16;

// ---------- workspace layout (bytes) ----------
#define WS_OFFSETS  64                        // 9 ints
#define WS_NSLOT    128                       // 1 int
#define WS_NSLOT64  132                       // 1 int
#define WS_SLOTE    192                       // 40 ints
#define WS_SLOTMT   352                       // 40 ints
#define WS_SLOTE64  512                       // 72 ints
#define WS_SLOTMT64 832                       // 72 ints
#define WS_IDX      2048                      // 4096 ints
#define WS_PERM     (2048 + 4*NTOK)           // 4096 ints
#define WS_XG       65536                     // bf16 [4096][512]  (gathered x)
#define WS_W1T      (WS_XG + 2*NTOK*D)        // bf16 [8][2048][512]  (W1^T)
#define WS_W2T      (WS_W1T + 2*E*D*F)        // bf16 [8][512][2048]  (W2^T)
#define WS_H        (WS_W2T + 2*E*D*F)        // bf16 [4096][2048]  (hidden)

static __device__ __forceinline__ u16 f2b(float f) {
  union { float f; unsigned u; } v; v.f = f;
  unsigned r = v.u + 0x7fffu + ((v.u >> 16) & 1u);   // RNE fp32->bf16
  return (u16)(r >> 16);
}

static __device__ __forceinline__ void gload16(const void* g, void* l) {
  __builtin_amdgcn_global_load_lds(
      (const __attribute__((address_space(1))) unsigned int*)g,
      (__attribute__((address_space(3))) unsigned int*)l, 16, 0, 0);
}

// ---------- gate: fp32-exact logits + argmax (NO atomics) ----------
__global__ __launch_bounds__(256) void gate_k(const float* __restrict__ x,
                                              const float* __restrict__ Wg,
                                              const float* __restrict__ bg,
                                              int* __restrict__ idx) {
  int tok = blockIdx.x * 4 + (threadIdx.x >> 6);   // one wave per token
  int l = threadIdx.x & 63;
  const float* xr = x + (size_t)tok * D;
  float acc[E];
#pragma unroll
  for (int e = 0; e < E; ++e) acc[e] = 0.f;
#pragma unroll
  for (int j = 0; j < 2; ++j) {
    float4 xv = *(const float4*)(xr + l * 8 + j * 4);
    float xs[4] = {xv.x, xv.y, xv.z, xv.w};
#pragma unroll
    for (int c = 0; c < 4; ++c) {
      int d = l * 8 + j * 4 + c;
      float4 w0 = *(const float4*)(Wg + d * 8);
      float4 w1 = *(const float4*)(Wg + d * 8 + 4);
      acc[0] += xs[c] * w0.x; acc[1] += xs[c] * w0.y;
      acc[2] += xs[c] * w0.z; acc[3] += xs[c] * w0.w;
      acc[4] += xs[c] * w1.x; acc[5] += xs[c] * w1.y;
      acc[6] += xs[c] * w1.z; acc[7] += xs[c] * w1.w;
    }
  }
#pragma unroll
  for (int off = 32; off; off >>= 1)
#pragma unroll
    for (int e = 0; e < E; ++e) acc[e] += __shfl_xor(acc[e], off, 64);
  if (l == 0) {
    float bv = acc[0] + bg[0]; int bi = 0;
#pragma unroll
    for (int e = 1; e < E; ++e) {           // strict > : first-max tie-break (matches argmax)
      float v = acc[e] + bg[e];
      if (v > bv) { bv = v; bi = e; }
    }
    idx[tok] = bi;
  }
}

// ---------- single block: LDS histogram -> offsets -> permutation + maps ----
__global__ __launch_bounds__(1024) void hist_perm_k(const int* __restrict__ idx,
                                                    int* __restrict__ offsets,
                                                    int* __restrict__ perm,
                                                    int* __restrict__ nslot,
                                                    int* __restrict__ slot_e,
                                                    int* __restrict__ slot_mt,
                                                    int* __restrict__ nslot64,
                                                    int* __restrict__ slot_e64,
                                                    int* __restrict__ slot_mt64) {
  __shared__ int wcnt[16][E];    // per-wave histograms / later cursors
  __shared__ int wbase[16][E];
  __shared__ int offs[E + 1];
  int t = threadIdx.x;
  int w = t >> 6;
  if (t < 16 * E) ((int*)wcnt)[t] = 0;
  __syncthreads();
  int e0[4];
#pragma unroll
  for (int j = 0; j < 4; ++j) {
    e0[j] = idx[t * 4 + j];
    atomicAdd(&wcnt[w][e0[j]], 1);
  }
  __syncthreads();
  if (t < 64) {
    // linear index li = e*16 + ww (expert-major) matches cursor-assignment order
    int li0 = 2 * t, li1 = 2 * t + 1;
    int c0 = wcnt[li0 & 15][li0 >> 4];
    int c1 = wcnt[li1 & 15][li1 >> 4];
    int s = c0 + c1;
    int incl = s;
#pragma unroll
    for (int o = 1; o < 64; o <<= 1) {
      int v = __shfl_up(incl, o, 64);
      if (t >= o) incl += v;
    }
    int excl = incl - s;
    wbase[li0 & 15][li0 >> 4] = excl;
    wbase[li1 & 15][li1 >> 4] = excl + c0;
    if ((li0 & 15) == 0) offs[li0 >> 4] = excl;   // start of expert li0>>4
    if (t == 63) offs[E] = incl;                  // total
  }
  __syncthreads();
  if (t < E + 1) offsets[t] = offs[t];
  if (t == 0) {                 // build (expert, m-tile) slot maps
    int ns = 0, ns64 = 0;
    for (int e = 0; e < E; ++e) {
      int c = offs[e + 1] - offs[e];
      int nmt = (c + 127) >> 7;
      for (int m = 0; m < nmt; ++m) { slot_e[ns] = e; slot_mt[ns] = m; ++ns; }
      int nmt64 = (c + 63) >> 6;
      for (int m = 0; m < nmt64; ++m) { slot_e64[ns64] = e; slot_mt64[ns64] = m; ++ns64; }
    }
    *nslot = ns;
    *nslot64 = ns64;
  }
  if (t < 16 * E) ((int*)wcnt)[t] = ((int*)wbase)[t];   // reuse as cursors
  __syncthreads();
#pragma unroll
  for (int j = 0; j < 4; ++j) {
    int pos = atomicAdd(&wcnt[w][e0[j]], 1);
    perm[pos] = t * 4 + j;
  }
}

// ---------- gather x rows in permuted order, convert to bf16 ----------
__global__ __launch_bounds__(256) void gather_x(const float* __restrict__ x,
                                                const int* __restrict__ perm,
                                                u16* __restrict__ xg) {
  int t = blockIdx.x * 256 + threadIdx.x;
  int r = t >> 7;              // 128 threads per row
  int c = (t & 127) << 2;
  float4 v = *(const float4*)(x + (size_t)perm[r] * D + c);
  ushort4 o; o.x = f2b(v.x); o.y = f2b(v.y); o.z = f2b(v.z); o.w = f2b(v.w);
  *(ushort4*)(xg + (size_t)r * D + c) = o;
}

// ---------- transpose+convert BOTH weights: fp32 [E][R][C] -> bf16 [E][C][R] --
__global__ __launch_bounds__(256) void transpose2_cvt(const float* __restrict__ W1,
                                                      u16* __restrict__ w1t,
                                                      const float* __restrict__ W2,
                                                      u16* __restrict__ w2t) {
  __shared__ float tile[64][65];
  int e = blockIdx.y;
  int bt = blockIdx.x;          // 0..255 -> W1, 256..511 -> W2
  const float* src; u16* dst; int R, C;
  if (bt < 256) { src = W1; dst = w1t; R = D; C = F; }
  else          { src = W2; dst = w2t; R = F; C = D; bt -= 256; }
  int tilesC = C >> 6;
  int trow = (bt / tilesC) << 6;
  int tcol = (bt % tilesC) << 6;
  const float* s = src + (size_t)e * R * C;
  u16* d = dst + (size_t)e * R * C;
  int lr = threadIdx.x >> 4;          // 0..15
  int lc = (threadIdx.x & 15) << 2;   // 0..60
#pragma unroll
  for (int i = 0; i < 64; i += 16) {
    float4 v = *(const float4*)(s + (size_t)(trow + lr + i) * C + tcol + lc);
    tile[lr + i][lc + 0] = v.x; tile[lr + i][lc + 1] = v.y;
    tile[lr + i][lc + 2] = v.z; tile[lr + i][lc + 3] = v.w;
  }
  __syncthreads();
#pragma unroll
  for (int i = 0; i < 64; i += 16) {
    int c = lr + i;                   // col of src tile = row of dst
    ushort4 o;
    o.x = f2b(tile[lc + 0][c]); o.y = f2b(tile[lc + 1][c]);
    o.z = f2b(tile[lc + 2][c]); o.w = f2b(tile[lc + 3][c]);
    *(ushort4*)(d + (size_t)(tcol + c) * R + trow + lc) = o;
  }
}

// ---------- grouped GEMM, TMx128 tile, BK=64, double-buffered 2-phase, ----
// ---------- T2 XOR-swizzled LDS, T1 XCD swizzle, slot map, SPLITK=1     ----
// A: bf16 [4096][K] row-major (rows grouped by expert); B: bf16 [E][N][K] (B^T)
// FUSE1: out = relu(acc + bias)        -> bf16 Hout[4096][N]
// else : out[perm[row]] = acc + bias   -> fp32 Fout (full-K direct write)
template <int K, int NBLK, int TM, bool FUSE1>
__global__ __launch_bounds__(256) void gemm_grouped(
    const u16* __restrict__ A, const u16* __restrict__ B,
    const float* __restrict__ bias, const int* __restrict__ offsets,
    const int* __restrict__ nslot, const int* __restrict__ slot_e,
    const int* __restrict__ slot_mt, const int* __restrict__ perm,
    u16* __restrict__ Hout, float* __restrict__ Fout) {
  constexpr int N = NBLK * 128;
  constexpr int NT = K / 64;              // 64-wide K-steps
  constexpr int RA = TM / 32;             // A staging rounds (32 rows each)
  constexpr int FM = TM / 32;             // m-fragments per wave
  constexpr int ASZ = TM * 64;            // u16 per A stage
  constexpr int BSZ = 128 * 64;           // u16 per B stage
  __shared__ u16 smem[2 * (ASZ + BSZ)];

  // T1: bijective XCD swizzle (gridDim.x % 8 == 0); nt fastest for A reuse.
  int nwg = gridDim.x;
  int b0 = blockIdx.x;
  int bid = (b0 & 7) * (nwg >> 3) + (b0 >> 3);
  int nt = bid % NBLK;
  int slot = bid / NBLK;
  if (slot >= *nslot) return;
  int e = slot_e[slot];
  int mt = slot_mt[slot];
  int off = offsets[e];
  int cnt = offsets[e + 1] - off;

  int t = threadIdx.x;
  int w = t >> 6;
  int l = t & 63;

  // ---- staging geometry: per round r, wave w covers rows r*32+w*8..+8,
  // lane l -> row r*32+w*8+(l>>3), 16B chunk. Source chunk swizzled so that a
  // LINEAR gload_lds dest gives LDS phys chunk p holding logical kc = p^(row&7).
  int rl_base = w * 8 + (l >> 3);
  int cchunk = (l & 7) ^ (l >> 3);        // logical source chunk for phys l&7
  const u16* Ap[RA];
  const u16* Bp[4];
  const u16* Beb = B + (size_t)e * N * K + (size_t)(nt * 128) * K;
#pragma unroll
  for (int r = 0; r < RA; ++r) {
    int ga = off + mt * TM + r * 32 + rl_base;
    if (ga > NTOK - 1) ga = NTOK - 1;
    Ap[r] = A + (size_t)ga * K + cchunk * 8;
  }
#pragma unroll
  for (int r = 0; r < 4; ++r)
    Bp[r] = Beb + (size_t)(r * 32 + rl_base) * K + cchunk * 8;

  int wr = (w >> 1) * (TM / 2);           // wave output sub-tile (TM/2)x64
  int wc = (w & 1) * 64;
  int lm = l & 15;
  int g = l >> 4;

  f32x4 acc[FM][4] = {};

  auto stage = [&](int cur, int k0) {
    u16* bA = smem + cur * (ASZ + BSZ);
    u16* bB = bA + ASZ;
#pragma unroll
    for (int r = 0; r < RA; ++r)
      gload16(Ap[r] + k0, bA + (r * 32 + w * 8) * 64 + l * 8);
#pragma unroll
    for (int r = 0; r < 4; ++r)
      gload16(Bp[r] + k0, bB + (r * 32 + w * 8) * 64 + l * 8);
  };
  auto compute = [&](int cur) {
    const u16* bA = smem + cur * (ASZ + BSZ);
    const u16* bB = bA + ASZ;
    __builtin_amdgcn_s_setprio(1);
#pragma unroll
    for (int kc = 0; kc < 2; ++kc) {
      bf16x8 av[FM], bv[4];
#pragma unroll
      for (int fm = 0; fm < FM; ++fm)
        av[fm] = *(const bf16x8*)&bA[(wr + fm * 16 + lm) * 64 +
                                     (((kc * 4 + g) ^ (lm & 7)) * 8)];
#pragma unroll
      for (int fn = 0; fn < 4; ++fn)
        bv[fn] = *(const bf16x8*)&bB[(wc + fn * 16 + lm) * 64 +
                                     (((kc * 4 + g) ^ (lm & 7)) * 8)];
#pragma unroll
      for (int fm = 0; fm < FM; ++fm)
#pragma unroll
        for (int fn = 0; fn < 4; ++fn)
          acc[fm][fn] = __builtin_amdgcn_mfma_f32_16x16x32_bf16(av[fm], bv[fn],
                                                                acc[fm][fn], 0, 0, 0);
    }
    __builtin_amdgcn_s_setprio(0);
  };

  // 2-phase pipeline: STAGE(next) overlaps compute(cur); one barrier per K-step.
  stage(0, 0);
  __syncthreads();
  int cur = 0;
#pragma unroll 2
  for (int tstep = 0; tstep < NT - 1; ++tstep) {
    stage(cur ^ 1, (tstep + 1) * 64);
    compute(cur);
    __syncthreads();
    cur ^= 1;
  }
  compute(cur);

  // epilogue: C/D layout col = lane&15, row = (lane>>4)*4 + reg
  int nbase = nt * 128 + wc;
  float bb[4];
#pragma unroll
  for (int fn = 0; fn < 4; ++fn) bb[fn] = bias[e * N + nbase + fn * 16 + lm];
#pragma unroll
  for (int fm = 0; fm < FM; ++fm) {
    int mbase = wr + fm * 16 + g * 4;
#pragma unroll
    for (int r = 0; r < 4; ++r) {
      int m = mt * TM + mbase + r;
      if (m < cnt) {
        size_t grow = (size_t)(off + m);
        if constexpr (FUSE1) {
#pragma unroll
          for (int fn = 0; fn < 4; ++fn) {
            float v = acc[fm][fn][r] + bb[fn];
            Hout[grow * N + nbase + fn * 16 + lm] = f2b(fmaxf(v, 0.f));
          }
        } else {
          size_t gout = (size_t)perm[grow];
#pragma unroll
          for (int fn = 0; fn < 4; ++fn)
            Fout[gout * N + nbase + fn * 16 + lm] = acc[fm][fn][r] + bb[fn];
        }
      }
    }
  }
}

extern "C" void kernel_launch(void* const* d_in, const int* in_sizes, int n_in,
                              void* d_out, int out_size, void* d_ws, size_t ws_size,
                              hipStream_t stream) {
  const float* x  = (const float*)d_in[0];
  const float* Wg = (const float*)d_in[1];
  const float* bg = (const float*)d_in[2];
  const float* W1 = (const float*)d_in[3];
  const float* b1 = (const float*)d_in[4];
  const float* W2 = (const float*)d_in[5];
  const float* b2 = (const float*)d_in[6];
  float* out = (float*)d_out;
  char* ws = (char*)d_ws;

  int* offsets  = (int*)(ws + WS_OFFSETS);
  int* nslot    = (int*)(ws + WS_NSLOT);
  int* nslot64  = (int*)(ws + WS_NSLOT64);
  int* slot_e   = (int*)(ws + WS_SLOTE);
  int* slot_mt  = (int*)(ws + WS_SLOTMT);
  int* slot_e64 = (int*)(ws + WS_SLOTE64);
  int* slot_mt64= (int*)(ws + WS_SLOTMT64);
  int* idx      = (int*)(ws + WS_IDX);
  int* perm     = (int*)(ws + WS_PERM);
  u16* xg  = (u16*)(ws + WS_XG);
  u16* w1t = (u16*)(ws + WS_W1T);
  u16* w2t = (u16*)(ws + WS_W2T);
  u16* h   = (u16*)(ws + WS_H);

  gate_k<<<NTOK / 4, 256, 0, stream>>>(x, Wg, bg, idx);
  hist_perm_k<<<1, 1024, 0, stream>>>(idx, offsets, perm, nslot, slot_e, slot_mt,
                                      nslot64, slot_e64, slot_mt64);
  gather_x<<<NTOK * D / 4 / 256, 256, 0, stream>>>(x, perm, xg);
  transpose2_cvt<<<dim3(512, E), 256, 0, stream>>>(W1, w1t, W2, w2t);
  gemm_grouped<D, F / 128, 128, true>
      <<<MAXSLOTS * (F / 128), 256, 0, stream>>>(xg, w1t, b1, offsets, nslot,
                                                 slot_e, slot_mt, perm, h, nullptr);
  gemm_grouped<F, D / 128, 64, false>
      <<<MAXSLOTS64 * (D / 128), 256, 0, stream>>>(h, w2t, b2, offsets, nslot64,
                                                   slot_e64, slot_mt64, perm,
                                                   nullptr, out);
}